// Round 7
// baseline (566.920 us; speedup 1.0000x reference)
//
#include <hip/hip_runtime.h>
#include <hip/hip_bf16.h>
#include <hip/hip_cooperative_groups.h>
#include <math.h>

namespace cg = cooperative_groups;

#define HC 64
#define DD 128
#define BSH 7       // bucket = 128 consecutive ids
#define BW  128
#define KMAX 512    // max buckets; ids must fit 16 bits (N <= 65536)
#define CHUNK 4096  // edges per partition chunk
#define CAP 8192    // LDS sort capacity in bucket phase (entries)
#define CAPB 6144   // padded per-bucket capacity (avg 4224, +29 sigma safe)

typedef __attribute__((ext_vector_type(8))) short bf16x8;
typedef __attribute__((ext_vector_type(4))) float f32x4;

// round-to-nearest-even f32 -> bf16 bits (inputs finite)
__device__ __forceinline__ unsigned short f2bf(float f) {
  unsigned u = __float_as_uint(f);
  return (unsigned short)((u + 0x7fffu + ((u >> 16) & 1u)) >> 16);
}

__device__ __forceinline__ float lrelu_clamp(float a) {
  a = (a > 0.f) ? a : 0.2f * a;
  return fminf(a, 43.f);
}

// ===================== MEGA (cooperative, 1 dispatch) =====================
struct MegaArgs {
  const float* h_x; const float* t_x;
  const float* Wsrc; const float* Wdst;
  const float* att_src; const float* att_dst;
  const float* bias;
  const int* src; const int* dst;
  unsigned short* Bt;
  __hip_bfloat16* xsA; __hip_bfloat16* xsB;
  float* lsA; float* ldB; float* lsB; float* ldA;
  int* gcurA; int* gcurB;
  int* rowT; int* rowH;
  unsigned* partA; unsigned* partB;
  int* csrT; int* csrH;
  float* out_h; float* out_t;
  int NH, NT, E, NL, KA, KB;
};

union SMem {
  struct { unsigned raw[CHUNK]; unsigned stage[CHUNK];
           int lcnt[KMAX]; int lbase[KMAX]; int lcur[KMAX]; int gbase[KMAX]; } part; // 40960 B
  struct { int sbuf[CAP]; int hist[BW + 1]; int cur[BW]; int red[512]; } bkt;        // 35844 B
  struct { int lds[8 * 232]; } msg;                                                  // 7424 B
};

__global__ __launch_bounds__(512) void mega(MegaArgs a)
{
  cg::grid_group grid = cg::this_grid();
  __shared__ SMem sm;
  const int tid = threadIdx.x;
  const int E2 = a.E + a.NL;
  const int tilesH = (a.NH + 127) >> 7, tilesT = (a.NT + 127) >> 7;
  const int ntiles = tilesH + tilesT;
  const int nchunks = (E2 + CHUNK - 1) / CHUNK;
  const float LOG2E = 1.44269504f;

  // ---------------- phase 0: Bt build + cursor zero ----------------
  if (blockIdx.x == 0) {
    for (int i = tid; i < 80 * DD; i += 512) {
      int j = i >> 7, k = i & 127;
      float v = 0.f;
      if (j < 64) {
        v = a.Wsrc[k * HC + j];
      } else if (j < 68) {
        int hh = j - 64;
        const float* W = (hh < 2) ? a.Wsrc : a.Wdst;
        const float* at = (hh < 2) ? a.att_src : a.att_dst;
        int h = hh & 1;
        float s = 0.f;
        for (int c = 0; c < 32; ++c)
          s = fmaf(W[k * HC + h * 32 + c], at[h * 32 + c], s);
        v = s * LOG2E;
      }
      a.Bt[j * DD + k] = f2bf(v);
    }
  } else if (blockIdx.x == 1) {
    for (int i = tid; i < a.KA + a.KB; i += 512) a.gcurA[i] = 0;  // gcurB contiguous
  }
  __threadfence();
  grid.sync();

  // ---------------- phase 1: node transform ∥ edge partition ----------------
  for (int it = blockIdx.x; it < ntiles + nchunks; it += gridDim.x) {
    if (it < ntiles) {
      // ----- node tile (8 waves x 16 nodes), B from global Bt (L2-hot) -----
      const float* x; __hip_bfloat16* xs; float* logit_s; float* logit_d; int N, blk;
      if (it < tilesH) { x = a.h_x; xs = a.xsA; logit_s = a.lsA; logit_d = a.ldB; N = a.NH; blk = it; }
      else { x = a.t_x; xs = a.xsB; logit_s = a.lsB; logit_d = a.ldA; N = a.NT; blk = it - tilesH; }
      int wid = tid >> 6, lane = tid & 63, m = lane & 15, kg = lane >> 4;
      int nbase = (blk * 8 + wid) * 16;
      if (nbase < N) {
        int nrow = nbase + m;
        int nclamp = (nrow < N) ? nrow : (N - 1);
        bf16x8 ahi[4], alo[4];
        const float* xrow = x + (size_t)nclamp * DD + kg * 8;
        #pragma unroll
        for (int kt = 0; kt < 4; ++kt) {
          float4 v0 = *(const float4*)(xrow + kt * 32);
          float4 v1 = *(const float4*)(xrow + kt * 32 + 4);
          float vv[8] = {v0.x, v0.y, v0.z, v0.w, v1.x, v1.y, v1.z, v1.w};
          #pragma unroll
          for (int i = 0; i < 8; ++i) {
            float v = vv[i];
            v = (v > 0.f) ? v : (exp2f(v * 1.44269504f) - 1.f);   // elu
            unsigned hb = __float_as_uint(v) & 0xffff0000u;
            ahi[kt][i] = (short)(hb >> 16);
            alo[kt][i] = (short)f2bf(v - __uint_as_float(hb));
          }
        }
        f32x4 acc[5];
        #pragma unroll
        for (int ct = 0; ct < 5; ++ct) acc[ct] = (f32x4){0.f, 0.f, 0.f, 0.f};
        const unsigned short* bbase = a.Bt + m * DD + kg * 8;
        #pragma unroll
        for (int ct = 0; ct < 5; ++ct) {
          #pragma unroll
          for (int kt = 0; kt < 4; ++kt) {
            bf16x8 b = *(const bf16x8*)(bbase + ct * 16 * DD + kt * 32);
            acc[ct] = __builtin_amdgcn_mfma_f32_16x16x32_bf16(ahi[kt], b, acc[ct], 0, 0, 0);
            acc[ct] = __builtin_amdgcn_mfma_f32_16x16x32_bf16(alo[kt], b, acc[ct], 0, 0, 0);
          }
        }
        int r0 = kg * 4;
        unsigned short* xsu = (unsigned short*)xs;
        #pragma unroll
        for (int ct = 0; ct < 4; ++ct) {
          #pragma unroll
          for (int r = 0; r < 4; ++r) {
            int n = nbase + r0 + r;
            if (n < N) xsu[(size_t)n * HC + ct * 16 + m] = f2bf(acc[ct][r]);
          }
        }
        if (m < 4) {
          float* dstp = (m < 2) ? logit_s : logit_d;
          int h = m & 1;
          #pragma unroll
          for (int r = 0; r < 4; ++r) {
            int n = nbase + r0 + r;
            if (n < N) dstp[n * 2 + h] = acc[4][r];
          }
        }
      }
    } else {
      // ----- partition chunk: edges read once, both passes from LDS -----
      int bid = it - ntiles;
      int base = bid * CHUNK;
      int lim = base + CHUNK < E2 ? base + CHUNK : E2;
      int cnt = lim - base;
      for (int i = base + tid; i < lim; i += 512) {
        unsigned s, d;
        if (i < a.E) { s = (unsigned)a.src[i]; d = (unsigned)a.dst[i]; }
        else         { s = d = (unsigned)(i - a.E); }
        sm.part.raw[i - base] = s | (d << 16);
      }
      __syncthreads();
      for (int p = 0; p < 2; ++p) {
        const int K = p ? a.KB : a.KA;
        int* gcur = p ? a.gcurB : a.gcurA;
        unsigned* outp = p ? a.partB : a.partA;
        for (int k2 = tid; k2 < K; k2 += 512) sm.part.lcnt[k2] = 0;
        __syncthreads();
        for (int i = tid; i < cnt; i += 512) {
          unsigned w = sm.part.raw[i];
          unsigned key = p ? (w & 0xffffu) : (w >> 16);
          atomicAdd(&sm.part.lcnt[key >> BSH], 1);
        }
        __syncthreads();
        if (tid < 64) {                      // wave-0 exclusive scan
          int carry = 0;
          for (int c0 = 0; c0 < K; c0 += 64) {
            int c = c0 + tid;
            int v = (c < K) ? sm.part.lcnt[c] : 0;
            int inc = v;
            #pragma unroll
            for (int o = 1; o < 64; o <<= 1) {
              int u = __shfl_up(inc, o, 64);
              if (tid >= o) inc += u;
            }
            if (c < K) sm.part.lbase[c] = inc - v + carry;
            carry += __shfl(inc, 63, 64);
          }
        }
        __syncthreads();
        for (int k2 = tid; k2 < K; k2 += 512) {
          sm.part.lcur[k2] = sm.part.lbase[k2];
          sm.part.gbase[k2] = atomicAdd(&gcur[k2], sm.part.lcnt[k2]);
        }
        __syncthreads();
        for (int i = tid; i < cnt; i += 512) {
          unsigned w = sm.part.raw[i];
          unsigned key = p ? (w & 0xffffu) : (w >> 16);
          unsigned val = p ? (w >> 16) : (w & 0xffffu);
          int pos = atomicAdd(&sm.part.lcur[key >> BSH], 1);
          sm.part.stage[pos] = val | (key << 16);
        }
        __syncthreads();
        for (int i = tid; i < cnt; i += 512) {
          unsigned wv = sm.part.stage[i];
          int kk = wv >> (16 + BSH);
          outp[(size_t)kk * CAPB + sm.part.gbase[kk] + (i - sm.part.lbase[kk])] = wv;
        }
        __syncthreads();
      }
    }
  }
  __threadfence();
  grid.sync();

  // ---------------- phase 2: per-bucket sort -> compact CSR ----------------
  for (int bb = blockIdx.x; bb < a.KA + a.KB; bb += gridDim.x) {
    const unsigned* part; const int* cntp; int* csr; int* row; int k, K, N;
    if (bb < a.KA) { k = bb; part = a.partA; cntp = a.gcurA; csr = a.csrT; row = a.rowT; K = a.KA; N = a.NT; }
    else { k = bb - a.KA; part = a.partB; cntp = a.gcurB; csr = a.csrH; row = a.rowH; K = a.KB; N = a.NH; }

    int psum = 0;
    for (int j = tid; j < k; j += 512) psum += cntp[j];
    sm.bkt.red[tid] = psum; __syncthreads();
    for (int s = 256; s > 0; s >>= 1) {
      if (tid < s) sm.bkt.red[tid] += sm.bkt.red[tid + s];
      __syncthreads();
    }
    int beg = sm.bkt.red[0];
    int cnt = cntp[k];
    size_t kbase = (size_t)k * CAPB;
    int d0 = k << BSH;
    int width = (BW < N - d0) ? BW : (N - d0);

    for (int i = tid; i <= BW; i += 512) sm.bkt.hist[i] = 0;
    __syncthreads();
    for (int i = tid; i < cnt; i += 512)
      atomicAdd(&sm.bkt.hist[(part[kbase + i] >> 16) & (BW - 1)], 1);
    __syncthreads();
    if (tid == 0) {
      int run = 0;
      for (int j = 0; j < width; ++j) { int c = sm.bkt.hist[j]; sm.bkt.hist[j] = run; run += c; }
      sm.bkt.hist[width] = run;
    }
    __syncthreads();
    if (tid < width) { sm.bkt.cur[tid] = sm.bkt.hist[tid]; row[d0 + tid] = beg + sm.bkt.hist[tid]; }
    if (k == K - 1 && tid == 0) row[N] = E2;
    __syncthreads();
    if (cnt <= CAP) {
      for (int i = tid; i < cnt; i += 512) {
        unsigned wv = part[kbase + i];
        int pos = atomicAdd(&sm.bkt.cur[(wv >> 16) & (BW - 1)], 1);
        sm.bkt.sbuf[pos] = wv & 0xFFFF;
      }
      __syncthreads();
      for (int i = tid; i < cnt; i += 512) csr[beg + i] = sm.bkt.sbuf[i];
    } else {
      for (int i = tid; i < cnt; i += 512) {
        unsigned wv = part[kbase + i];
        int pos = atomicAdd(&sm.bkt.cur[(wv >> 16) & (BW - 1)], 1);
        csr[beg + pos] = wv & 0xFFFF;
      }
    }
    __syncthreads();
  }
  __threadfence();
  grid.sync();

  // ---------------- phase 3: message (8 waves x 2 dsts = 16/block) ----------
  {
    int wid = tid >> 6, lane = tid & 63, l31 = lane & 31, half = lane >> 5;
    int head = l31 >> 4;
    int* L = sm.msg.lds + wid * 232;
    float* Lf = (float*)L;
    int sv_w = (half ? 40 : 0) + l31;
    int w0_w = (half ? 160 : 80) + l31;
    int w1_w = (half ? 200 : 120) + l31;
    const int4*   svq = (const int4*)  (L  + (half ? 40 : 0));
    const float4* wq  = (const float4*)(Lf + (half ? (head ? 200 : 160)
                                                   : (head ? 120 : 80)));
    int ngA = (a.NT + 15) >> 4, ngB = (a.NH + 15) >> 4;
    for (int g = blockIdx.x; g < ngA + ngB; g += gridDim.x) {
      const int* row; const int* csr_src; const float* logit_s; const float* logit_d;
      const __hip_bfloat16* xs; float* out; int Nd, gblk;
      if (g < ngA) { row = a.rowT; csr_src = a.csrT; logit_s = a.lsA; logit_d = a.ldA; xs = a.xsA; out = a.out_t; Nd = a.NT; gblk = g; }
      else { row = a.rowH; csr_src = a.csrH; logit_s = a.lsB; logit_d = a.ldB; xs = a.xsB; out = a.out_h; Nd = a.NH; gblk = g - ngA; }
      const unsigned* xs2 = (const unsigned*)xs;
      const float2* ls2 = (const float2*)logit_s;

      int d = gblk * 16 + (wid << 1) + half;
      int beg = 0, end = 0;
      float2 ld2 = {0.f, 0.f};
      if (d < Nd) {
        beg = row[d]; end = row[d + 1];
        ld2 = ((const float2*)logit_d)[d];
      }
      int nt = ((end - beg) + 31) >> 5;
      nt = max(nt, __shfl_xor(nt, 32, 64));

      float2 accA = {0.f, 0.f}, accB = {0.f, 0.f};
      float s0 = 0.f, s1 = 0.f;
      int myPos = beg;

#define STEP(SV, W, ACC) {                                         \
      unsigned xv = xs2[(SV) * 32 + l31];                          \
      ACC.x = fmaf((W), __uint_as_float(xv << 16), ACC.x);         \
      ACC.y = fmaf((W), __uint_as_float(xv & 0xffff0000u), ACC.y); \
    }
      for (int tile = 0; tile < nt; ++tile, myPos += 32) {
        int tc = end - myPos; tc = tc < 0 ? 0 : (tc > 32 ? 32 : tc);
        int sv = 0; float e0 = 0.f, e1 = 0.f;
        if (l31 < tc) {
          sv = csr_src[myPos + l31];
          float2 l2 = ls2[sv];
          e0 = exp2f(lrelu_clamp(l2.x + ld2.x));
          e1 = exp2f(lrelu_clamp(l2.y + ld2.y));
        }
        s0 += e0; s1 += e1;
        L[sv_w]  = sv;
        Lf[w0_w] = e0;
        Lf[w1_w] = e1;
        asm volatile("s_waitcnt lgkmcnt(0)" ::: "memory");
        int tcmax = max(tc, __shfl_xor(tc, 32, 64));
        int nq = (tcmax + 3) >> 2;
        for (int q = 0; q < nq; ++q) {
          int4   s4 = svq[q];
          float4 w4 = wq[q];
          STEP(s4.x, w4.x, accA)
          STEP(s4.y, w4.y, accB)
          STEP(s4.z, w4.z, accA)
          STEP(s4.w, w4.w, accB)
        }
      }
#undef STEP
      #pragma unroll
      for (int off = 16; off > 0; off >>= 1) {
        s0 += __shfl_xor(s0, off, 64);
        s1 += __shfl_xor(s1, off, 64);
      }
      float sD = (l31 & 16) ? s1 : s0;
      float inv = 1.f / (sD + 1e-16f);
      if (d < Nd) {
        float2 b2 = ((const float2*)a.bias)[l31];
        float2 o;
        o.x = (accA.x + accB.x) * inv + b2.x;
        o.y = (accA.y + accB.y) * inv + b2.y;
        ((float2*)out)[(size_t)d * 32 + l31] = o;
      }
    }
  }
}

// ===================== fallback path (R6 kernels, verbatim) =====================
__global__ __launch_bounds__(128) void build_bt(
    const float* __restrict__ Wsrc, const float* __restrict__ Wdst,
    const float* __restrict__ att_src, const float* __restrict__ att_dst,
    unsigned short* __restrict__ Bt, int* __restrict__ gcur, int KK)
{
  int j = blockIdx.x;
  int k = threadIdx.x;
  const float LOG2E = 1.44269504f;
  float v = 0.f;
  if (j < 64) {
    v = Wsrc[k * HC + j];
  } else if (j < 68) {
    int hh = j - 64;
    const float* W = (hh < 2) ? Wsrc : Wdst;
    const float* a = (hh < 2) ? att_src : att_dst;
    int h = hh & 1;
    float s = 0.f;
    for (int c = 0; c < 32; ++c)
      s = fmaf(W[k * HC + h * 32 + c], a[h * 32 + c], s);
    v = s * LOG2E;
  }
  Bt[j * DD + k] = f2bf(v);
  if (j == 0) {
    for (int i = k; i < KK; i += 128) gcur[i] = 0;
  }
}

__global__ __launch_bounds__(512) void fused_front(
    const float* __restrict__ xH, const float* __restrict__ xT,
    const unsigned short* __restrict__ Bt,
    __hip_bfloat16* __restrict__ xsH, __hip_bfloat16* __restrict__ xsT,
    float* __restrict__ lsH, float* __restrict__ ldH,
    float* __restrict__ lsT, float* __restrict__ ldT,
    int NH, int NT, int blocksH, int nodeB,
    const int* __restrict__ src, const int* __restrict__ dst, int E, int NL,
    int* __restrict__ gcurA, int* __restrict__ gcurB,
    unsigned int* __restrict__ partA, unsigned int* __restrict__ partB,
    int KA, int KB)
{
  __shared__ unsigned int raw[CHUNK];
  __shared__ unsigned int stage[CHUNK];
  __shared__ int lcnt[KMAX];
  __shared__ int lbase[KMAX];
  __shared__ int lcur[KMAX];
  __shared__ int gbase[KMAX];
  int tid = threadIdx.x;

  if ((int)blockIdx.x < nodeB) {
    const float* x; __hip_bfloat16* xs; float* logit_s; float* logit_d; int N, blk;
    if ((int)blockIdx.x < blocksH) { x = xH; xs = xsH; logit_s = lsH; logit_d = ldH; N = NH; blk = blockIdx.x; }
    else { x = xT; xs = xsT; logit_s = lsT; logit_d = ldT; N = NT; blk = blockIdx.x - blocksH; }
    int wid  = tid >> 6;
    int lane = tid & 63;
    int m    = lane & 15;
    int kg   = lane >> 4;
    int nbase = (blk * 8 + wid) * 16;
    if (nbase >= N) return;
    int nrow = nbase + m;
    int nclamp = (nrow < N) ? nrow : (N - 1);
    bf16x8 ahi[4], alo[4];
    const float* xrow = x + (size_t)nclamp * DD + kg * 8;
    #pragma unroll
    for (int kt = 0; kt < 4; ++kt) {
      float4 v0 = *(const float4*)(xrow + kt * 32);
      float4 v1 = *(const float4*)(xrow + kt * 32 + 4);
      float vv[8] = {v0.x, v0.y, v0.z, v0.w, v1.x, v1.y, v1.z, v1.w};
      #pragma unroll
      for (int i = 0; i < 8; ++i) {
        float v = vv[i];
        v = (v > 0.f) ? v : (exp2f(v * 1.44269504f) - 1.f);
        unsigned hb = __float_as_uint(v) & 0xffff0000u;
        ahi[kt][i] = (short)(hb >> 16);
        alo[kt][i] = (short)f2bf(v - __uint_as_float(hb));
      }
    }
    f32x4 acc[5];
    #pragma unroll
    for (int ct = 0; ct < 5; ++ct) acc[ct] = (f32x4){0.f, 0.f, 0.f, 0.f};
    const unsigned short* bbase = Bt + m * DD + kg * 8;
    #pragma unroll
    for (int ct = 0; ct < 5; ++ct) {
      #pragma unroll
      for (int kt = 0; kt < 4; ++kt) {
        bf16x8 b = *(const bf16x8*)(bbase + ct * 16 * DD + kt * 32);
        acc[ct] = __builtin_amdgcn_mfma_f32_16x16x32_bf16(ahi[kt], b, acc[ct], 0, 0, 0);
        acc[ct] = __builtin_amdgcn_mfma_f32_16x16x32_bf16(alo[kt], b, acc[ct], 0, 0, 0);
      }
    }
    int r0 = kg * 4;
    unsigned short* xsu = (unsigned short*)xs;
    #pragma unroll
    for (int ct = 0; ct < 4; ++ct) {
      #pragma unroll
      for (int r = 0; r < 4; ++r) {
        int n = nbase + r0 + r;
        if (n < N) xsu[(size_t)n * HC + ct * 16 + m] = f2bf(acc[ct][r]);
      }
    }
    if (m < 4) {
      float* dstp = (m < 2) ? logit_s : logit_d;
      int h = m & 1;
      #pragma unroll
      for (int r = 0; r < 4; ++r) {
        int n = nbase + r0 + r;
        if (n < N) dstp[n * 2 + h] = acc[4][r];
      }
    }
    return;
  }

  int bid = blockIdx.x - nodeB;
  int base = bid * CHUNK;
  int E2 = E + NL;
  int lim = base + CHUNK < E2 ? base + CHUNK : E2;
  int cnt = lim - base;
  for (int i = base + tid; i < lim; i += 512) {
    unsigned s, d;
    if (i < E) { s = (unsigned)src[i]; d = (unsigned)dst[i]; }
    else       { s = d = (unsigned)(i - E); }
    raw[i - base] = s | (d << 16);
  }
  __syncthreads();
  for (int p = 0; p < 2; ++p) {
    const int K = p ? KB : KA;
    int* gcur = p ? gcurB : gcurA;
    unsigned int* outp = p ? partB : partA;
    for (int k2 = tid; k2 < K; k2 += 512) lcnt[k2] = 0;
    __syncthreads();
    for (int i = tid; i < cnt; i += 512) {
      unsigned w = raw[i];
      unsigned key = p ? (w & 0xffffu) : (w >> 16);
      atomicAdd(&lcnt[key >> BSH], 1);
    }
    __syncthreads();
    if (tid < 64) {
      int carry = 0;
      for (int c0 = 0; c0 < K; c0 += 64) {
        int c = c0 + tid;
        int v = (c < K) ? lcnt[c] : 0;
        int inc = v;
        #pragma unroll
        for (int o = 1; o < 64; o <<= 1) {
          int u = __shfl_up(inc, o, 64);
          if (tid >= o) inc += u;
        }
        if (c < K) lbase[c] = inc - v + carry;
        carry += __shfl(inc, 63, 64);
      }
    }
    __syncthreads();
    for (int k2 = tid; k2 < K; k2 += 512) {
      lcur[k2] = lbase[k2];
      gbase[k2] = atomicAdd(&gcur[k2], lcnt[k2]);
    }
    __syncthreads();
    for (int i = tid; i < cnt; i += 512) {
      unsigned w = raw[i];
      unsigned key = p ? (w & 0xffffu) : (w >> 16);
      unsigned val = p ? (w >> 16) : (w & 0xffffu);
      int pos = atomicAdd(&lcur[key >> BSH], 1);
      stage[pos] = val | (key << 16);
    }
    __syncthreads();
    for (int i = tid; i < cnt; i += 512) {
      unsigned wv = stage[i];
      int kk = wv >> (16 + BSH);
      outp[(size_t)kk * CAPB + gbase[kk] + (i - lbase[kk])] = wv;
    }
    __syncthreads();
  }
}

__global__ __launch_bounds__(256) void bucket_csr4(
    const unsigned int* __restrict__ partA, const int* __restrict__ cntA,
    int KA, int NA,
    const unsigned int* __restrict__ partB, const int* __restrict__ cntB,
    int KB, int NB,
    int E2, int* __restrict__ csrA, int* __restrict__ rowA,
    int* __restrict__ csrB, int* __restrict__ rowB)
{
  __shared__ int sbuf[CAP];
  __shared__ int hist[BW + 1];
  __shared__ int cur[BW];
  __shared__ int red[256];
  const unsigned int* part; const int* cntp;
  int* csr; int* row; int k, K, N;
  if ((int)blockIdx.x < KA) { k = blockIdx.x; part = partA; cntp = cntA; csr = csrA; row = rowA; K = KA; N = NA; }
  else { k = blockIdx.x - KA; part = partB; cntp = cntB; csr = csrB; row = rowB; K = KB; N = NB; }
  int tid = threadIdx.x;
  int psum = 0;
  for (int j = tid; j < k; j += 256) psum += cntp[j];
  red[tid] = psum; __syncthreads();
  for (int s = 128; s > 0; s >>= 1) {
    if (tid < s) red[tid] += red[tid + s];
    __syncthreads();
  }
  int beg = red[0];
  int cnt = cntp[k];
  size_t kbase = (size_t)k * CAPB;
  int d0 = k << BSH;
  int width = (BW < N - d0) ? BW : (N - d0);
  for (int i = tid; i <= BW; i += 256) hist[i] = 0;
  __syncthreads();
  for (int i = tid; i < cnt; i += 256)
    atomicAdd(&hist[(part[kbase + i] >> 16) & (BW - 1)], 1);
  __syncthreads();
  if (tid == 0) {
    int run = 0;
    for (int j = 0; j < width; ++j) { int c = hist[j]; hist[j] = run; run += c; }
    hist[width] = run;
  }
  __syncthreads();
  if (tid < width) { cur[tid] = hist[tid]; row[d0 + tid] = beg + hist[tid]; }
  if (k == K - 1 && tid == 0) row[N] = E2;
  __syncthreads();
  if (cnt <= CAP) {
    for (int i = tid; i < cnt; i += 256) {
      unsigned int wv = part[kbase + i];
      int pos = atomicAdd(&cur[(wv >> 16) & (BW - 1)], 1);
      sbuf[pos] = wv & 0xFFFF;
    }
    __syncthreads();
    for (int i = tid; i < cnt; i += 256) csr[beg + i] = sbuf[i];
  } else {
    for (int i = tid; i < cnt; i += 256) {
      unsigned int wv = part[kbase + i];
      int pos = atomicAdd(&cur[(wv >> 16) & (BW - 1)], 1);
      csr[beg + pos] = wv & 0xFFFF;
    }
  }
}

__global__ __launch_bounds__(256) void csr_message5(
    const int* __restrict__ rowA, const int* __restrict__ csrA,
    const float* __restrict__ lsA, const float* __restrict__ ldA,
    const __hip_bfloat16* __restrict__ xsA, float* __restrict__ outA, int NdA,
    const int* __restrict__ rowB, const int* __restrict__ csrB,
    const float* __restrict__ lsB, const float* __restrict__ ldB,
    const __hip_bfloat16* __restrict__ xsB, float* __restrict__ outB, int NdB,
    const float* __restrict__ bias, int blocksA)
{
  const int* row; const int* csr_src; const float* logit_s; const float* logit_d;
  const __hip_bfloat16* xs; float* out; int Nd, blk;
  if ((int)blockIdx.x < blocksA) { row = rowA; csr_src = csrA; logit_s = lsA; logit_d = ldA; xs = xsA; out = outA; Nd = NdA; blk = blockIdx.x; }
  else { row = rowB; csr_src = csrB; logit_s = lsB; logit_d = ldB; xs = xsB; out = outB; Nd = NdB; blk = blockIdx.x - blocksA; }
  __shared__ int lds[4 * 232];
  int tid  = threadIdx.x;
  int wid  = tid >> 6;
  int lane = tid & 63;
  int l31  = lane & 31;
  int half = lane >> 5;
  int head = l31 >> 4;
  int* L = &lds[wid * 232];
  float* Lf = (float*)L;
  int sv_w = (half ? 40 : 0) + l31;
  int w0_w = (half ? 160 : 80) + l31;
  int w1_w = (half ? 200 : 120) + l31;
  const int4*   svq = (const int4*)  (L  + (half ? 40 : 0));
  const float4* wq  = (const float4*)(Lf + (half ? (head ? 200 : 160)
                                                 : (head ? 120 : 80)));
  const unsigned* xs2 = (const unsigned*)xs;
  const float2* ls2 = (const float2*)logit_s;
  int d = blk * 8 + (wid << 1) + half;
  int beg = 0, end = 0;
  float2 ld2 = {0.f, 0.f};
  if (d < Nd) {
    beg = row[d]; end = row[d + 1];
    ld2 = ((const float2*)logit_d)[d];
  }
  int nt = ((end - beg) + 31) >> 5;
  nt = max(nt, __shfl_xor(nt, 32, 64));
  float2 accA = {0.f, 0.f}, accB = {0.f, 0.f};
  float s0 = 0.f, s1 = 0.f;
  int myPos = beg;
#define STEP(SV, W, ACC) {                                         \
    unsigned xv = xs2[(SV) * 32 + l31];                            \
    ACC.x = fmaf((W), __uint_as_float(xv << 16), ACC.x);           \
    ACC.y = fmaf((W), __uint_as_float(xv & 0xffff0000u), ACC.y);   \
  }
  for (int tile = 0; tile < nt; ++tile, myPos += 32) {
    int tc = end - myPos; tc = tc < 0 ? 0 : (tc > 32 ? 32 : tc);
    int sv = 0; float e0 = 0.f, e1 = 0.f;
    if (l31 < tc) {
      sv = csr_src[myPos + l31];
      float2 l2 = ls2[sv];
      e0 = exp2f(lrelu_clamp(l2.x + ld2.x));
      e1 = exp2f(lrelu_clamp(l2.y + ld2.y));
    }
    s0 += e0; s1 += e1;
    L[sv_w]  = sv;
    Lf[w0_w] = e0;
    Lf[w1_w] = e1;
    asm volatile("s_waitcnt lgkmcnt(0)" ::: "memory");
    int tcmax = max(tc, __shfl_xor(tc, 32, 64));
    int nq = (tcmax + 3) >> 2;
    for (int q = 0; q < nq; ++q) {
      int4   s4 = svq[q];
      float4 w4 = wq[q];
      STEP(s4.x, w4.x, accA)
      STEP(s4.y, w4.y, accB)
      STEP(s4.z, w4.z, accA)
      STEP(s4.w, w4.w, accB)
    }
  }
#undef STEP
  #pragma unroll
  for (int off = 16; off > 0; off >>= 1) {
    s0 += __shfl_xor(s0, off, 64);
    s1 += __shfl_xor(s1, off, 64);
  }
  float sD = (l31 & 16) ? s1 : s0;
  float inv = 1.f / (sD + 1e-16f);
  if (d < Nd) {
    float2 b2 = ((const float2*)bias)[l31];
    float2 o;
    o.x = (accA.x + accB.x) * inv + b2.x;
    o.y = (accA.y + accB.y) * inv + b2.y;
    ((float2*)out)[(size_t)d * 32 + l31] = o;
  }
}

extern "C" void kernel_launch(void* const* d_in, const int* in_sizes, int n_in,
                              void* d_out, int out_size, void* d_ws, size_t ws_size,
                              hipStream_t stream)
{
  const float* h_x   = (const float*)d_in[0];
  const float* t_x   = (const float*)d_in[1];
  const int*   edge  = (const int*)d_in[2];
  const float* W_src = (const float*)d_in[3];
  const float* W_dst = (const float*)d_in[4];
  const float* att_s = (const float*)d_in[5];
  const float* att_d = (const float*)d_in[6];
  const float* bias  = (const float*)d_in[7];

  int NH = in_sizes[0] / DD;
  int NT = in_sizes[1] / DD;
  int E  = in_sizes[2] / 2;
  int NL = (NH < NT) ? NH : NT;
  int E2 = E + NL;
  const int* srcA = edge;
  const int* dstA = edge + E;

  int KA = (NT + BW - 1) >> BSH;
  int KB = (NH + BW - 1) >> BSH;
  int B  = (E2 + CHUNK - 1) / CHUNK;

  char* w = (char*)d_ws;
  size_t used = 0;
  auto alloc = [&](size_t bytes) {
    char* p = w + used; used = (used + bytes + 255) & ~(size_t)255; return p;
  };
  __hip_bfloat16* xsA = (__hip_bfloat16*)alloc((size_t)NH * HC * 2);
  __hip_bfloat16* xsB = (__hip_bfloat16*)alloc((size_t)NT * HC * 2);
  float* lsA  = (float*)alloc((size_t)NH * 2 * 4);
  float* ldB  = (float*)alloc((size_t)NH * 2 * 4);
  float* lsB  = (float*)alloc((size_t)NT * 2 * 4);
  float* ldA  = (float*)alloc((size_t)NT * 2 * 4);
  int* gcur   = (int*)alloc((size_t)(KA + KB) * 4);
  int* gcurA  = gcur;
  int* gcurB  = gcur + KA;
  int* rowT   = (int*)alloc((size_t)(NT + 1) * 4);
  int* rowH   = (int*)alloc((size_t)(NH + 1) * 4);
  unsigned int* partA = (unsigned int*)alloc((size_t)KA * CAPB * 4);
  unsigned int* partB = (unsigned int*)alloc((size_t)KB * CAPB * 4);
  int* csrT   = (int*)alloc((size_t)E2 * 4);
  int* csrH   = (int*)alloc((size_t)E2 * 4);
  unsigned short* Bt = (unsigned short*)alloc((size_t)80 * DD * 2);

  float* out   = (float*)d_out;
  float* out_h = out;
  float* out_t = out + (size_t)NH * HC;

  // ---- cooperative capability + grid sizing (cached) ----
  static int coop = -1;
  static int gridSize = 0;
  if (coop < 0) {
    int dev = 0; hipGetDevice(&dev);
    int ca = 0;
    hipDeviceGetAttribute(&ca, hipDeviceAttributeCooperativeLaunch, dev);
    int nCU = 0;
    hipDeviceGetAttribute(&nCU, hipDeviceAttributeMultiprocessorCount, dev);
    int nbpc = 0;
    hipError_t e = hipOccupancyMaxActiveBlocksPerMultiprocessor(
        &nbpc, (const void*)mega, 512, 0);
    if (e != hipSuccess || nbpc < 1 || nCU < 1) ca = 0;
    gridSize = nCU * nbpc;
    coop = ca ? 1 : 0;
  }

  if (coop && gridSize > 1) {
    MegaArgs ma;
    ma.h_x = h_x; ma.t_x = t_x; ma.Wsrc = W_src; ma.Wdst = W_dst;
    ma.att_src = att_s; ma.att_dst = att_d; ma.bias = bias;
    ma.src = srcA; ma.dst = dstA; ma.Bt = Bt;
    ma.xsA = xsA; ma.xsB = xsB;
    ma.lsA = lsA; ma.ldB = ldB; ma.lsB = lsB; ma.ldA = ldA;
    ma.gcurA = gcurA; ma.gcurB = gcurB;
    ma.rowT = rowT; ma.rowH = rowH;
    ma.partA = partA; ma.partB = partB;
    ma.csrT = csrT; ma.csrH = csrH;
    ma.out_h = out_h; ma.out_t = out_t;
    ma.NH = NH; ma.NT = NT; ma.E = E; ma.NL = NL; ma.KA = KA; ma.KB = KB;
    void* args[] = { &ma };
    hipError_t err = hipLaunchCooperativeKernel(
        (const void*)mega, dim3(gridSize), dim3(512), args, 0, stream);
    if (err == hipSuccess) return;
    coop = 0;   // fall through to multi-dispatch path
  }

  // ---- fallback: proven 4-dispatch path (R6) ----
  build_bt<<<80, 128, 0, stream>>>(W_src, W_dst, att_s, att_d, Bt,
                                   gcur, KA + KB);
  int bH = (NH + 127) / 128, bT = (NT + 127) / 128;
  int nodeB = bH + bT;
  fused_front<<<nodeB + B, 512, 0, stream>>>(
      h_x, t_x, Bt, xsA, xsB, lsA, ldB, lsB, ldA, NH, NT, bH, nodeB,
      srcA, dstA, E, NL, gcurA, gcurB, partA, partB, KA, KB);
  bucket_csr4<<<KA + KB, 256, 0, stream>>>(
      partA, gcurA, KA, NT, partB, gcurB, KB, NH,
      E2, csrT, rowT, csrH, rowH);
  int gA = (NT + 7) / 8, gB = (NH + 7) / 8;
  csr_message5<<<gA + gB, 256, 0, stream>>>(
      rowT, csrT, lsA, ldA, xsA, out_t, NT,
      rowH, csrH, lsB, ldB, xsB, out_h, NH, bias, gA);
}

// Round 8
// 263.399 us; speedup vs baseline: 2.1523x; 2.1523x over previous
//
#include <hip/hip_runtime.h>
#include <hip/hip_bf16.h>
#include <math.h>

#define HC 64
#define DD 128
#define BSH 7       // bucket = 128 consecutive ids
#define BW  128
#define KMAX 512    // max buckets; ids must fit 16 bits (N <= 65536)
#define CHUNK 4096  // edges per partition chunk
#define CAP 8192    // LDS sort capacity in bucket_message (entries; avg 4224, +61 sigma)
#define CAPB 6144   // padded per-bucket capacity (avg 4224, +29 sigma safe)

typedef __attribute__((ext_vector_type(8))) short bf16x8;
typedef __attribute__((ext_vector_type(4))) float f32x4;

// round-to-nearest-even f32 -> bf16 bits (inputs finite)
__device__ __forceinline__ unsigned short f2bf(float f) {
  unsigned u = __float_as_uint(f);
  return (unsigned short)((u + 0x7fffu + ((u >> 16) & 1u)) >> 16);
}

__device__ __forceinline__ float lrelu_clamp(float a) {
  a = (a > 0.f) ? a : 0.2f * a;
  return fminf(a, 43.f);
}

// ---------------- build folded B matrix [80][128] bf16 + zero cursors ----
__global__ __launch_bounds__(128) void build_bt(
    const float* __restrict__ Wsrc, const float* __restrict__ Wdst,
    const float* __restrict__ att_src, const float* __restrict__ att_dst,
    unsigned short* __restrict__ Bt, int* __restrict__ gcur, int KK)
{
  int j = blockIdx.x;      // 0..79
  int k = threadIdx.x;     // 0..127
  const float LOG2E = 1.44269504f;
  float v = 0.f;
  if (j < 64) {
    v = Wsrc[k * HC + j];
  } else if (j < 68) {
    int hh = j - 64;
    const float* W = (hh < 2) ? Wsrc : Wdst;
    const float* a = (hh < 2) ? att_src : att_dst;
    int h = hh & 1;
    float s = 0.f;
    for (int c = 0; c < 32; ++c)
      s = fmaf(W[k * HC + h * 32 + c], a[h * 32 + c], s);
    v = s * LOG2E;
  }
  Bt[j * DD + k] = f2bf(v);
  if (j == 0) {
    for (int i = k; i < KK; i += 128) gcur[i] = 0;
  }
}

// ---------------- fused front: node transform (MFMA) + edge partition ----
// (R6 structure, verbatim) Blocks [0,nodeB): node transform, 8 waves x 16
// nodes. Blocks [nodeB,nodeB+B): partition; edges read once into LDS, both
// bucket passes from LDS; spans reserved via device-scope atomicAdd on gcur.
__global__ __launch_bounds__(512) void fused_front(
    const float* __restrict__ xH, const float* __restrict__ xT,
    const unsigned short* __restrict__ Bt,
    __hip_bfloat16* __restrict__ xsH, __hip_bfloat16* __restrict__ xsT,
    float* __restrict__ lsH, float* __restrict__ ldH,
    float* __restrict__ lsT, float* __restrict__ ldT,
    int NH, int NT, int blocksH, int nodeB,
    const int* __restrict__ src, const int* __restrict__ dst, int E, int NL,
    int* __restrict__ gcurA, int* __restrict__ gcurB,
    unsigned int* __restrict__ partA, unsigned int* __restrict__ partB,
    int KA, int KB)
{
  __shared__ unsigned int raw[CHUNK];    // 16 KB  (s | d<<16)
  __shared__ unsigned int stage[CHUNK];  // 16 KB
  __shared__ int lcnt[KMAX];
  __shared__ int lbase[KMAX];
  __shared__ int lcur[KMAX];
  __shared__ int gbase[KMAX];
  int tid = threadIdx.x;

  if ((int)blockIdx.x < nodeB) {
    const float* x; __hip_bfloat16* xs; float* logit_s; float* logit_d; int N, blk;
    if ((int)blockIdx.x < blocksH) { x = xH; xs = xsH; logit_s = lsH; logit_d = ldH; N = NH; blk = blockIdx.x; }
    else { x = xT; xs = xsT; logit_s = lsT; logit_d = ldT; N = NT; blk = blockIdx.x - blocksH; }
    int wid  = tid >> 6;
    int lane = tid & 63;
    int m    = lane & 15;
    int kg   = lane >> 4;
    int nbase = (blk * 8 + wid) * 16;
    if (nbase >= N) return;
    int nrow = nbase + m;
    int nclamp = (nrow < N) ? nrow : (N - 1);
    bf16x8 ahi[4], alo[4];
    const float* xrow = x + (size_t)nclamp * DD + kg * 8;
    #pragma unroll
    for (int kt = 0; kt < 4; ++kt) {
      float4 v0 = *(const float4*)(xrow + kt * 32);
      float4 v1 = *(const float4*)(xrow + kt * 32 + 4);
      float vv[8] = {v0.x, v0.y, v0.z, v0.w, v1.x, v1.y, v1.z, v1.w};
      #pragma unroll
      for (int i = 0; i < 8; ++i) {
        float v = vv[i];
        v = (v > 0.f) ? v : (exp2f(v * 1.44269504f) - 1.f);   // elu
        unsigned hb = __float_as_uint(v) & 0xffff0000u;       // truncate -> hi
        ahi[kt][i] = (short)(hb >> 16);
        alo[kt][i] = (short)f2bf(v - __uint_as_float(hb));    // exact residual
      }
    }
    f32x4 acc[5];
    #pragma unroll
    for (int ct = 0; ct < 5; ++ct) acc[ct] = (f32x4){0.f, 0.f, 0.f, 0.f};
    const unsigned short* bbase = Bt + m * DD + kg * 8;
    #pragma unroll
    for (int ct = 0; ct < 5; ++ct) {
      #pragma unroll
      for (int kt = 0; kt < 4; ++kt) {
        bf16x8 b = *(const bf16x8*)(bbase + ct * 16 * DD + kt * 32);
        acc[ct] = __builtin_amdgcn_mfma_f32_16x16x32_bf16(ahi[kt], b, acc[ct], 0, 0, 0);
        acc[ct] = __builtin_amdgcn_mfma_f32_16x16x32_bf16(alo[kt], b, acc[ct], 0, 0, 0);
      }
    }
    int r0 = kg * 4;
    unsigned short* xsu = (unsigned short*)xs;
    #pragma unroll
    for (int ct = 0; ct < 4; ++ct) {
      #pragma unroll
      for (int r = 0; r < 4; ++r) {
        int n = nbase + r0 + r;
        if (n < N) xsu[(size_t)n * HC + ct * 16 + m] = f2bf(acc[ct][r]);
      }
    }
    if (m < 4) {
      float* dstp = (m < 2) ? logit_s : logit_d;
      int h = m & 1;
      #pragma unroll
      for (int r = 0; r < 4; ++r) {
        int n = nbase + r0 + r;
        if (n < N) dstp[n * 2 + h] = acc[4][r];
      }
    }
    return;
  }

  int bid = blockIdx.x - nodeB;
  int base = bid * CHUNK;
  int E2 = E + NL;
  int lim = base + CHUNK < E2 ? base + CHUNK : E2;
  int cnt = lim - base;
  for (int i = base + tid; i < lim; i += 512) {
    unsigned s, d;
    if (i < E) { s = (unsigned)src[i]; d = (unsigned)dst[i]; }
    else       { s = d = (unsigned)(i - E); }
    raw[i - base] = s | (d << 16);
  }
  __syncthreads();
  for (int p = 0; p < 2; ++p) {
    const int K = p ? KB : KA;
    int* gcur = p ? gcurB : gcurA;
    unsigned int* outp = p ? partB : partA;
    for (int k2 = tid; k2 < K; k2 += 512) lcnt[k2] = 0;
    __syncthreads();
    for (int i = tid; i < cnt; i += 512) {
      unsigned w = raw[i];
      unsigned key = p ? (w & 0xffffu) : (w >> 16);
      atomicAdd(&lcnt[key >> BSH], 1);
    }
    __syncthreads();
    if (tid < 64) {                      // wave-0 exclusive scan
      int carry = 0;
      for (int c0 = 0; c0 < K; c0 += 64) {
        int c = c0 + tid;
        int v = (c < K) ? lcnt[c] : 0;
        int inc = v;
        #pragma unroll
        for (int o = 1; o < 64; o <<= 1) {
          int u = __shfl_up(inc, o, 64);
          if (tid >= o) inc += u;
        }
        if (c < K) lbase[c] = inc - v + carry;
        carry += __shfl(inc, 63, 64);
      }
    }
    __syncthreads();
    for (int k2 = tid; k2 < K; k2 += 512) {
      lcur[k2] = lbase[k2];
      gbase[k2] = atomicAdd(&gcur[k2], lcnt[k2]);
    }
    __syncthreads();
    for (int i = tid; i < cnt; i += 512) {
      unsigned w = raw[i];
      unsigned key = p ? (w & 0xffffu) : (w >> 16);
      unsigned val = p ? (w >> 16) : (w & 0xffffu);
      int pos = atomicAdd(&lcur[key >> BSH], 1);
      stage[pos] = val | (key << 16);
    }
    __syncthreads();
    for (int i = tid; i < cnt; i += 512) {
      unsigned wv = stage[i];
      int kk = wv >> (16 + BSH);
      outp[(size_t)kk * CAPB + gbase[kk] + (i - lbase[kk])] = wv;
    }
    __syncthreads();
  }
}

// ---------------- bucket sort + message, fused (one block per bucket) -----
// Phase A: sort this bucket's ~4224 entries into LDS sbuf by dst low-7
// (exactly the old bucket_csr4 LDS sort; no global csr/row needed).
// Phase B: 8 passes x (8 waves x 2 dsts) = all 128 dsts of the bucket,
// message5 half-wave structure verbatim, sv read from LDS sbuf.
__global__ __launch_bounds__(512) void bucket_message(
    const unsigned* __restrict__ partA, const int* __restrict__ cntA, int KA, int NA,
    const unsigned* __restrict__ partB, const int* __restrict__ cntB, int KB, int NB,
    const float* __restrict__ lsA, const float* __restrict__ ldA,
    const __hip_bfloat16* __restrict__ xsA, float* __restrict__ outA,
    const float* __restrict__ lsB, const float* __restrict__ ldB,
    const __hip_bfloat16* __restrict__ xsB, float* __restrict__ outB,
    const float* __restrict__ bias)
{
  __shared__ int sbuf[CAP];        // 32 KB sorted src ids
  __shared__ int hist[BW + 1];
  __shared__ int cur[BW];
  __shared__ int mlds[8 * 232];    // 7.4 KB per-wave message strips

  const unsigned* part; const int* cntp; int k, N;
  const float* logit_s; const float* logit_d; const __hip_bfloat16* xs; float* out;
  if ((int)blockIdx.x < KA) {
    k = blockIdx.x; part = partA; cntp = cntA; N = NA;
    logit_s = lsA; logit_d = ldA; xs = xsA; out = outA;
  } else {
    k = blockIdx.x - KA; part = partB; cntp = cntB; N = NB;
    logit_s = lsB; logit_d = ldB; xs = xsB; out = outB;
  }

  int tid = threadIdx.x;
  int cnt = cntp[k];
  size_t kbase = (size_t)k * CAPB;
  int d0 = k << BSH;
  int width = (BW < N - d0) ? BW : (N - d0);

  // ---- phase A: LDS counting sort by dst low-7 ----
  for (int i = tid; i <= BW; i += 512) hist[i] = 0;
  __syncthreads();
  for (int i = tid; i < cnt; i += 512)
    atomicAdd(&hist[(part[kbase + i] >> 16) & (BW - 1)], 1);
  __syncthreads();
  if (tid == 0) {
    int run = 0;
    for (int j = 0; j < width; ++j) { int c = hist[j]; hist[j] = run; run += c; }
    hist[width] = run;
  }
  __syncthreads();
  if (tid < width) cur[tid] = hist[tid];
  __syncthreads();
  bool fits = (cnt <= CAP);
  if (fits) {
    for (int i = tid; i < cnt; i += 512) {
      unsigned wv = part[kbase + i];
      int pos = atomicAdd(&cur[(wv >> 16) & (BW - 1)], 1);
      sbuf[pos] = (int)(wv & 0xFFFFu);
    }
  }
  __syncthreads();

  // ---- phase B: message (8 waves x 2 dsts per pass, 8 passes) ----
  int wid  = tid >> 6;
  int lane = tid & 63;
  int l31  = lane & 31;
  int half = lane >> 5;
  int head = l31 >> 4;
  int* L = mlds + wid * 232;
  float* Lf = (float*)L;
  int sv_w = (half ? 40 : 0) + l31;
  int w0_w = (half ? 160 : 80) + l31;
  int w1_w = (half ? 200 : 120) + l31;
  const int4*   svq = (const int4*)  (L  + (half ? 40 : 0));
  const float4* wq  = (const float4*)(Lf + (half ? (head ? 200 : 160)
                                                 : (head ? 120 : 80)));
  const unsigned* xs2 = (const unsigned*)xs;
  const float2* ls2 = (const float2*)logit_s;

#define STEP(SV, W, ACC) {                                         \
    unsigned xv = xs2[(SV) * 32 + l31];                            \
    ACC.x = fmaf((W), __uint_as_float(xv << 16), ACC.x);           \
    ACC.y = fmaf((W), __uint_as_float(xv & 0xffff0000u), ACC.y);   \
  }

  if (fits) {
    for (int p = 0; p < 8; ++p) {
      int dl = p * 16 + (wid << 1) + half;      // 0..127 within bucket
      int d = d0 + dl;
      int beg = 0, end = 0;
      float2 ld2 = {0.f, 0.f};
      if (dl < width) {
        beg = hist[dl]; end = hist[dl + 1];
        ld2 = ((const float2*)logit_d)[d];
      }
      int nt = ((end - beg) + 31) >> 5;
      nt = max(nt, __shfl_xor(nt, 32, 64));     // wave-uniform tile count

      float2 accA = {0.f, 0.f}, accB = {0.f, 0.f};
      float s0 = 0.f, s1 = 0.f;
      int myPos = beg;
      for (int tile = 0; tile < nt; ++tile, myPos += 32) {
        int tc = end - myPos; tc = tc < 0 ? 0 : (tc > 32 ? 32 : tc);
        int sv = 0; float e0 = 0.f, e1 = 0.f;
        if (l31 < tc) {
          sv = sbuf[myPos + l31];               // LDS, not global csr
          float2 l2 = ls2[sv];
          e0 = exp2f(lrelu_clamp(l2.x + ld2.x));
          e1 = exp2f(lrelu_clamp(l2.y + ld2.y));
        }
        s0 += e0; s1 += e1;
        L[sv_w]  = sv;
        Lf[w0_w] = e0;
        Lf[w1_w] = e1;
        // same-wave cross-lane LDS RAW: DS in-order per wave; drain writes
        asm volatile("s_waitcnt lgkmcnt(0)" ::: "memory");
        int tcmax = max(tc, __shfl_xor(tc, 32, 64));
        int nq = (tcmax + 3) >> 2;
        for (int q = 0; q < nq; ++q) {
          int4   s4 = svq[q];
          float4 w4 = wq[q];
          STEP(s4.x, w4.x, accA)
          STEP(s4.y, w4.y, accB)
          STEP(s4.z, w4.z, accA)
          STEP(s4.w, w4.w, accB)
        }
      }
      #pragma unroll
      for (int off = 16; off > 0; off >>= 1) {
        s0 += __shfl_xor(s0, off, 64);
        s1 += __shfl_xor(s1, off, 64);
      }
      float sD = (l31 & 16) ? s1 : s0;
      float inv = 1.f / (sD + 1e-16f);
      if (dl < width) {
        float2 b2 = ((const float2*)bias)[l31];
        float2 o;
        o.x = (accA.x + accB.x) * inv + b2.x;
        o.y = (accA.y + accB.y) * inv + b2.y;
        ((float2*)out)[(size_t)d * 32 + l31] = o;
      }
    }
  } else {
    // fallback (bucket > CAP, statistically unreachable): filter-scan the
    // whole bucket per dst from global part; weight 0 kills non-matches.
    for (int p = 0; p < 8; ++p) {
      int dl = p * 16 + (wid << 1) + half;
      int d = d0 + dl;
      bool act = (dl < width);
      float2 ld2 = {0.f, 0.f};
      if (act) ld2 = ((const float2*)logit_d)[d];
      float2 accA = {0.f, 0.f}, accB = {0.f, 0.f};
      float s0 = 0.f, s1 = 0.f;
      for (int t0 = 0; t0 < cnt; t0 += 32) {
        int idx = t0 + l31;
        int sv = 0; float e0 = 0.f, e1 = 0.f;
        if (idx < cnt) {
          unsigned wv = part[kbase + idx];
          sv = (int)(wv & 0xFFFFu);
          if (act && (int)((wv >> 16) & (BW - 1)) == dl) {
            float2 l2 = ls2[sv];
            e0 = exp2f(lrelu_clamp(l2.x + ld2.x));
            e1 = exp2f(lrelu_clamp(l2.y + ld2.y));
          }
        }
        s0 += e0; s1 += e1;
        L[sv_w]  = sv;
        Lf[w0_w] = e0;
        Lf[w1_w] = e1;
        asm volatile("s_waitcnt lgkmcnt(0)" ::: "memory");
        int rem = cnt - t0; int tcmax = rem < 32 ? rem : 32;
        int nq = (tcmax + 3) >> 2;
        for (int q = 0; q < nq; ++q) {
          int4   s4 = svq[q];
          float4 w4 = wq[q];
          STEP(s4.x, w4.x, accA)
          STEP(s4.y, w4.y, accB)
          STEP(s4.z, w4.z, accA)
          STEP(s4.w, w4.w, accB)
        }
      }
      #pragma unroll
      for (int off = 16; off > 0; off >>= 1) {
        s0 += __shfl_xor(s0, off, 64);
        s1 += __shfl_xor(s1, off, 64);
      }
      float sD = (l31 & 16) ? s1 : s0;
      float inv = 1.f / (sD + 1e-16f);
      if (act) {
        float2 b2 = ((const float2*)bias)[l31];
        float2 o;
        o.x = (accA.x + accB.x) * inv + b2.x;
        o.y = (accA.y + accB.y) * inv + b2.y;
        ((float2*)out)[(size_t)d * 32 + l31] = o;
      }
    }
  }
#undef STEP
}

extern "C" void kernel_launch(void* const* d_in, const int* in_sizes, int n_in,
                              void* d_out, int out_size, void* d_ws, size_t ws_size,
                              hipStream_t stream)
{
  const float* h_x   = (const float*)d_in[0];
  const float* t_x   = (const float*)d_in[1];
  const int*   edge  = (const int*)d_in[2];
  const float* W_src = (const float*)d_in[3];
  const float* W_dst = (const float*)d_in[4];
  const float* att_s = (const float*)d_in[5];
  const float* att_d = (const float*)d_in[6];
  const float* bias  = (const float*)d_in[7];

  int NH = in_sizes[0] / DD;
  int NT = in_sizes[1] / DD;
  int E  = in_sizes[2] / 2;
  int NL = (NH < NT) ? NH : NT;
  int E2 = E + NL;
  const int* srcA = edge;       // row 0 (h index)
  const int* dstA = edge + E;   // row 1 (t index)

  int KA = (NT + BW - 1) >> BSH;   // pass A buckets (over t / dst)
  int KB = (NH + BW - 1) >> BSH;   // pass B buckets (over h / src)
  int B  = (E2 + CHUNK - 1) / CHUNK;

  char* w = (char*)d_ws;
  size_t used = 0;
  auto alloc = [&](size_t bytes) {
    char* p = w + used; used = (used + bytes + 255) & ~(size_t)255; return p;
  };
  __hip_bfloat16* xsA = (__hip_bfloat16*)alloc((size_t)NH * HC * 2);
  __hip_bfloat16* xsB = (__hip_bfloat16*)alloc((size_t)NT * HC * 2);
  float* lsA  = (float*)alloc((size_t)NH * 2 * 4);
  float* ldB  = (float*)alloc((size_t)NH * 2 * 4);
  float* lsB  = (float*)alloc((size_t)NT * 2 * 4);
  float* ldA  = (float*)alloc((size_t)NT * 2 * 4);
  int* gcur   = (int*)alloc((size_t)(KA + KB) * 4);      // bucket cursors
  int* gcurA  = gcur;
  int* gcurB  = gcur + KA;
  unsigned int* partA = (unsigned int*)alloc((size_t)KA * CAPB * 4);  // padded
  unsigned int* partB = (unsigned int*)alloc((size_t)KB * CAPB * 4);  // padded
  unsigned short* Bt = (unsigned short*)alloc((size_t)80 * DD * 2);

  float* out   = (float*)d_out;              // (h_rep [NH,64], t_rep [NT,64])
  float* out_h = out;
  float* out_t = out + (size_t)NH * HC;

  build_bt<<<80, 128, 0, stream>>>(W_src, W_dst, att_s, att_d, Bt,
                                   gcur, KA + KB);

  int bH = (NH + 127) / 128, bT = (NT + 127) / 128;
  int nodeB = bH + bT;
  fused_front<<<nodeB + B, 512, 0, stream>>>(
      h_x, t_x, Bt, xsA, xsB, lsA, ldB, lsB, ldA, NH, NT, bH, nodeB,
      srcA, dstA, E, NL, gcurA, gcurB, partA, partB, KA, KB);

  // pass A buckets (over t) -> t_rep ; pass B buckets (over h) -> h_rep
  bucket_message<<<KA + KB, 512, 0, stream>>>(
      partA, gcurA, KA, NT, partB, gcurB, KB, NH,
      lsA, ldA, xsA, out_t,
      lsB, ldB, xsB, out_h, bias);
}

// Round 9
// 210.335 us; speedup vs baseline: 2.6953x; 1.2523x over previous
//
#include <hip/hip_runtime.h>
#include <hip/hip_bf16.h>
#include <math.h>

#define HC 64
#define DD 128
#define BSH 7       // bucket = 128 consecutive ids
#define BW  128
#define KMAX 512    // max buckets; ids must fit 16 bits (N <= 65536)
#define CHUNK 4096  // edges per partition chunk
#define CAP 8192    // LDS sort capacity in bucket_csr (entries)
#define CAPB 6144   // padded per-bucket capacity (avg 4224, +29 sigma safe)

typedef __attribute__((ext_vector_type(8))) short bf16x8;
typedef __attribute__((ext_vector_type(4))) float f32x4;

// round-to-nearest-even f32 -> bf16 bits (inputs finite)
__device__ __forceinline__ unsigned short f2bf(float f) {
  unsigned u = __float_as_uint(f);
  return (unsigned short)((u + 0x7fffu + ((u >> 16) & 1u)) >> 16);
}

__device__ __forceinline__ float lrelu_clamp(float a) {
  a = (a > 0.f) ? a : 0.2f * a;
  return fminf(a, 43.f);
}

// ---------------- build folded B matrix [80][128] bf16 + zero cursors ----
__global__ __launch_bounds__(128) void build_bt(
    const float* __restrict__ Wsrc, const float* __restrict__ Wdst,
    const float* __restrict__ att_src, const float* __restrict__ att_dst,
    unsigned short* __restrict__ Bt, int* __restrict__ gcur, int KK)
{
  int j = blockIdx.x;      // 0..79
  int k = threadIdx.x;     // 0..127
  const float LOG2E = 1.44269504f;
  float v = 0.f;
  if (j < 64) {
    v = Wsrc[k * HC + j];
  } else if (j < 68) {
    int hh = j - 64;
    const float* W = (hh < 2) ? Wsrc : Wdst;
    const float* a = (hh < 2) ? att_src : att_dst;
    int h = hh & 1;
    float s = 0.f;
    for (int c = 0; c < 32; ++c)
      s = fmaf(W[k * HC + h * 32 + c], a[h * 32 + c], s);
    v = s * LOG2E;
  }
  Bt[j * DD + k] = f2bf(v);
  if (j == 0) {
    for (int i = k; i < KK; i += 128) gcur[i] = 0;
  }
}

// ---------------- fused front: edge partition + node transform (MFMA) ----
// Blocks [0, B): partition (started first: atomic-heavy, mixes with nodes).
// Blocks [B, B+nodeB): node transform, 8 waves x 16 nodes.
// LDS trimmed to 24 KB (stage + tables; edges re-read from global per pass)
// -> 4 blocks/CU = 32 waves/CU residency for BOTH phases (was 3/40KB/24w).
__global__ __launch_bounds__(512) void fused_front(
    const float* __restrict__ xH, const float* __restrict__ xT,
    const unsigned short* __restrict__ Bt,
    __hip_bfloat16* __restrict__ xsH, __hip_bfloat16* __restrict__ xsT,
    float* __restrict__ lsH, float* __restrict__ ldH,
    float* __restrict__ lsT, float* __restrict__ ldT,
    int NH, int NT, int blocksH, int B,
    const int* __restrict__ src, const int* __restrict__ dst, int E, int NL,
    int* __restrict__ gcurA, int* __restrict__ gcurB,
    unsigned int* __restrict__ partA, unsigned int* __restrict__ partB,
    int KA, int KB)
{
  __shared__ unsigned int stage[CHUNK];  // 16 KB
  __shared__ int lcnt[KMAX];             // 2 KB
  __shared__ int lbase[KMAX];            // 2 KB
  __shared__ int lcur[KMAX];             // 2 KB
  __shared__ int gbase[KMAX];            // 2 KB  -> 24 KB total
  int tid = threadIdx.x;

  if ((int)blockIdx.x >= B) {
    // ================= node transform via MFMA =================
    const float* x; __hip_bfloat16* xs; float* logit_s; float* logit_d; int N, blk;
    int nb = blockIdx.x - B;
    if (nb < blocksH) { x = xH; xs = xsH; logit_s = lsH; logit_d = ldH; N = NH; blk = nb; }
    else { x = xT; xs = xsT; logit_s = lsT; logit_d = ldT; N = NT; blk = nb - blocksH; }
    int wid  = tid >> 6;
    int lane = tid & 63;
    int m    = lane & 15;
    int kg   = lane >> 4;
    int nbase = (blk * 8 + wid) * 16;
    if (nbase >= N) return;
    int nrow = nbase + m;
    int nclamp = (nrow < N) ? nrow : (N - 1);
    bf16x8 ahi[4], alo[4];
    const float* xrow = x + (size_t)nclamp * DD + kg * 8;
    #pragma unroll
    for (int kt = 0; kt < 4; ++kt) {
      float4 v0 = *(const float4*)(xrow + kt * 32);
      float4 v1 = *(const float4*)(xrow + kt * 32 + 4);
      float vv[8] = {v0.x, v0.y, v0.z, v0.w, v1.x, v1.y, v1.z, v1.w};
      #pragma unroll
      for (int i = 0; i < 8; ++i) {
        float v = vv[i];
        v = (v > 0.f) ? v : (exp2f(v * 1.44269504f) - 1.f);   // elu
        unsigned hb = __float_as_uint(v) & 0xffff0000u;       // truncate -> hi
        ahi[kt][i] = (short)(hb >> 16);
        alo[kt][i] = (short)f2bf(v - __uint_as_float(hb));    // exact residual
      }
    }
    f32x4 acc[5];
    #pragma unroll
    for (int ct = 0; ct < 5; ++ct) acc[ct] = (f32x4){0.f, 0.f, 0.f, 0.f};
    const unsigned short* bbase = Bt + m * DD + kg * 8;
    #pragma unroll
    for (int ct = 0; ct < 5; ++ct) {
      #pragma unroll
      for (int kt = 0; kt < 4; ++kt) {
        bf16x8 b = *(const bf16x8*)(bbase + ct * 16 * DD + kt * 32);
        acc[ct] = __builtin_amdgcn_mfma_f32_16x16x32_bf16(ahi[kt], b, acc[ct], 0, 0, 0);
        acc[ct] = __builtin_amdgcn_mfma_f32_16x16x32_bf16(alo[kt], b, acc[ct], 0, 0, 0);
      }
    }
    int r0 = kg * 4;
    unsigned short* xsu = (unsigned short*)xs;
    #pragma unroll
    for (int ct = 0; ct < 4; ++ct) {
      #pragma unroll
      for (int r = 0; r < 4; ++r) {
        int n = nbase + r0 + r;
        if (n < N) xsu[(size_t)n * HC + ct * 16 + m] = f2bf(acc[ct][r]);
      }
    }
    if (m < 4) {
      float* dstp = (m < 2) ? logit_s : logit_d;
      int h = m & 1;
      #pragma unroll
      for (int r = 0; r < 4; ++r) {
        int n = nbase + r0 + r;
        if (n < N) dstp[n * 2 + h] = acc[4][r];
      }
    }
    return;
  }

  // ================= partition (edges re-read per pass; no raw buffer) ====
  int bid = blockIdx.x;
  int base = bid * CHUNK;
  int E2 = E + NL;
  int lim = base + CHUNK < E2 ? base + CHUNK : E2;
  int cnt = lim - base;

  for (int p = 0; p < 2; ++p) {
    const int K = p ? KB : KA;
    int* gcur = p ? gcurB : gcurA;
    unsigned int* outp = p ? partB : partA;

    for (int k2 = tid; k2 < K; k2 += 512) lcnt[k2] = 0;
    __syncthreads();
    for (int i = base + tid; i < lim; i += 512) {
      int s, d;
      if (i < E) { s = src[i]; d = dst[i]; } else { s = d = i - E; }
      int key = p ? s : d;
      atomicAdd(&lcnt[key >> BSH], 1);
    }
    __syncthreads();
    if (tid < 64) {                      // wave-0 exclusive scan over K counts
      int carry = 0;
      for (int c0 = 0; c0 < K; c0 += 64) {
        int c = c0 + tid;
        int v = (c < K) ? lcnt[c] : 0;
        int inc = v;
        #pragma unroll
        for (int o = 1; o < 64; o <<= 1) {
          int u = __shfl_up(inc, o, 64);
          if (tid >= o) inc += u;
        }
        if (c < K) lbase[c] = inc - v + carry;
        carry += __shfl(inc, 63, 64);
      }
    }
    __syncthreads();
    for (int k2 = tid; k2 < K; k2 += 512) {
      lcur[k2] = lbase[k2];
      gbase[k2] = atomicAdd(&gcur[k2], lcnt[k2]);   // reserve span in bucket
    }
    __syncthreads();
    for (int i = base + tid; i < lim; i += 512) {
      int s, d;
      if (i < E) { s = src[i]; d = dst[i]; } else { s = d = i - E; }
      int key = p ? s : d;
      int val = p ? d : s;
      int pos = atomicAdd(&lcur[key >> BSH], 1);
      stage[pos] = (unsigned)val | ((unsigned)key << 16);
    }
    __syncthreads();
    for (int i = tid; i < cnt; i += 512) {
      unsigned wv = stage[i];
      int kk = wv >> (16 + BSH);
      outp[(size_t)kk * CAPB + gbase[kk] + (i - lbase[kk])] = wv;
    }
    __syncthreads();    // stage/lcnt reused by next pass
  }
}

// per-bucket key-sort in LDS -> compact csr + row pointers; offset computed
// in-block (prefix over cnt[0..k)) - R6 verbatim.
__global__ __launch_bounds__(256) void bucket_csr4(
    const unsigned int* __restrict__ partA, const int* __restrict__ cntA,
    int KA, int NA,
    const unsigned int* __restrict__ partB, const int* __restrict__ cntB,
    int KB, int NB,
    int E2, int* __restrict__ csrA, int* __restrict__ rowA,
    int* __restrict__ csrB, int* __restrict__ rowB)
{
  __shared__ int sbuf[CAP];        // 32 KB
  __shared__ int hist[BW + 1];
  __shared__ int cur[BW];
  __shared__ int red[256];
  const unsigned int* part; const int* cntp;
  int* csr; int* row; int k, K, N;
  if ((int)blockIdx.x < KA) { k = blockIdx.x; part = partA; cntp = cntA; csr = csrA; row = rowA; K = KA; N = NA; }
  else { k = blockIdx.x - KA; part = partB; cntp = cntB; csr = csrB; row = rowB; K = KB; N = NB; }
  int tid = threadIdx.x;
  int psum = 0;
  for (int j = tid; j < k; j += 256) psum += cntp[j];
  red[tid] = psum; __syncthreads();
  for (int s = 128; s > 0; s >>= 1) {
    if (tid < s) red[tid] += red[tid + s];
    __syncthreads();
  }
  int beg = red[0];
  int cnt = cntp[k];
  size_t kbase = (size_t)k * CAPB;
  int d0 = k << BSH;
  int width = (BW < N - d0) ? BW : (N - d0);
  for (int i = tid; i <= BW; i += 256) hist[i] = 0;
  __syncthreads();
  for (int i = tid; i < cnt; i += 256)
    atomicAdd(&hist[(part[kbase + i] >> 16) & (BW - 1)], 1);
  __syncthreads();
  if (tid == 0) {
    int run = 0;
    for (int j = 0; j < width; ++j) { int c = hist[j]; hist[j] = run; run += c; }
    hist[width] = run;
  }
  __syncthreads();
  if (tid < width) { cur[tid] = hist[tid]; row[d0 + tid] = beg + hist[tid]; }
  if (k == K - 1 && tid == 0) row[N] = E2;
  __syncthreads();
  if (cnt <= CAP) {
    for (int i = tid; i < cnt; i += 256) {
      unsigned int wv = part[kbase + i];
      int pos = atomicAdd(&cur[(wv >> 16) & (BW - 1)], 1);
      sbuf[pos] = wv & 0xFFFF;
    }
    __syncthreads();
    for (int i = tid; i < cnt; i += 256) csr[beg + i] = sbuf[i];
  } else {
    for (int i = tid; i < cnt; i += 256) {   // fallback, never for uniform data
      unsigned int wv = part[kbase + i];
      int pos = atomicAdd(&cur[(wv >> 16) & (BW - 1)], 1);
      csr[beg + pos] = wv & 0xFFFF;
    }
  }
}

// ---------------- message stage (R5/R6 verbatim - FROZEN) ----------------
__global__ __launch_bounds__(256) void csr_message5(
    const int* __restrict__ rowA, const int* __restrict__ csrA,
    const float* __restrict__ lsA, const float* __restrict__ ldA,
    const __hip_bfloat16* __restrict__ xsA, float* __restrict__ outA, int NdA,
    const int* __restrict__ rowB, const int* __restrict__ csrB,
    const float* __restrict__ lsB, const float* __restrict__ ldB,
    const __hip_bfloat16* __restrict__ xsB, float* __restrict__ outB, int NdB,
    const float* __restrict__ bias, int blocksA)
{
  const int* row; const int* csr_src; const float* logit_s; const float* logit_d;
  const __hip_bfloat16* xs; float* out; int Nd, blk;
  if ((int)blockIdx.x < blocksA) { row = rowA; csr_src = csrA; logit_s = lsA; logit_d = ldA; xs = xsA; out = outA; Nd = NdA; blk = blockIdx.x; }
  else { row = rowB; csr_src = csrB; logit_s = lsB; logit_d = ldB; xs = xsB; out = outB; Nd = NdB; blk = blockIdx.x - blocksA; }

  __shared__ int lds[4 * 232];     // 3712 B
  int tid  = threadIdx.x;
  int wid  = tid >> 6;
  int lane = tid & 63;
  int l31  = lane & 31;
  int half = lane >> 5;
  int head = l31 >> 4;

  int* L = &lds[wid * 232];
  float* Lf = (float*)L;
  int sv_w = (half ? 40 : 0) + l31;
  int w0_w = (half ? 160 : 80) + l31;
  int w1_w = (half ? 200 : 120) + l31;
  const int4*   svq = (const int4*)  (L  + (half ? 40 : 0));
  const float4* wq  = (const float4*)(Lf + (half ? (head ? 200 : 160)
                                                 : (head ? 120 : 80)));
  const unsigned* xs2 = (const unsigned*)xs;
  const float2* ls2 = (const float2*)logit_s;

  int d = blk * 8 + (wid << 1) + half;
  int beg = 0, end = 0;
  float2 ld2 = {0.f, 0.f};
  if (d < Nd) {
    beg = row[d]; end = row[d + 1];
    ld2 = ((const float2*)logit_d)[d];
  }

  int nt = ((end - beg) + 31) >> 5;
  nt = max(nt, __shfl_xor(nt, 32, 64));

  float2 accA = {0.f, 0.f}, accB = {0.f, 0.f};
  float s0 = 0.f, s1 = 0.f;
  int myPos = beg;

#define STEP(SV, W, ACC) {                                         \
    unsigned xv = xs2[(SV) * 32 + l31];                            \
    ACC.x = fmaf((W), __uint_as_float(xv << 16), ACC.x);           \
    ACC.y = fmaf((W), __uint_as_float(xv & 0xffff0000u), ACC.y);   \
  }

  for (int tile = 0; tile < nt; ++tile, myPos += 32) {
    int tc = end - myPos; tc = tc < 0 ? 0 : (tc > 32 ? 32 : tc);
    int sv = 0; float e0 = 0.f, e1 = 0.f;
    if (l31 < tc) {
      sv = csr_src[myPos + l31];
      float2 l2 = ls2[sv];
      e0 = exp2f(lrelu_clamp(l2.x + ld2.x));
      e1 = exp2f(lrelu_clamp(l2.y + ld2.y));
    }
    s0 += e0; s1 += e1;
    L[sv_w]  = sv;
    Lf[w0_w] = e0;
    Lf[w1_w] = e1;
    // same-wave cross-lane LDS RAW: DS in-order per wave; drain writes
    asm volatile("s_waitcnt lgkmcnt(0)" ::: "memory");
    int tcmax = max(tc, __shfl_xor(tc, 32, 64));
    int nq = (tcmax + 3) >> 2;
    for (int q = 0; q < nq; ++q) {
      int4   s4 = svq[q];
      float4 w4 = wq[q];
      STEP(s4.x, w4.x, accA)
      STEP(s4.y, w4.y, accB)
      STEP(s4.z, w4.z, accA)
      STEP(s4.w, w4.w, accB)
    }
  }
#undef STEP

  #pragma unroll
  for (int off = 16; off > 0; off >>= 1) {
    s0 += __shfl_xor(s0, off, 64);
    s1 += __shfl_xor(s1, off, 64);
  }
  float sD = (l31 & 16) ? s1 : s0;
  float inv = 1.f / (sD + 1e-16f);

  if (d < Nd) {
    float2 b2 = ((const float2*)bias)[l31];
    float2 o;
    o.x = (accA.x + accB.x) * inv + b2.x;
    o.y = (accA.y + accB.y) * inv + b2.y;
    ((float2*)out)[(size_t)d * 32 + l31] = o;
  }
}

extern "C" void kernel_launch(void* const* d_in, const int* in_sizes, int n_in,
                              void* d_out, int out_size, void* d_ws, size_t ws_size,
                              hipStream_t stream)
{
  const float* h_x   = (const float*)d_in[0];
  const float* t_x   = (const float*)d_in[1];
  const int*   edge  = (const int*)d_in[2];
  const float* W_src = (const float*)d_in[3];
  const float* W_dst = (const float*)d_in[4];
  const float* att_s = (const float*)d_in[5];
  const float* att_d = (const float*)d_in[6];
  const float* bias  = (const float*)d_in[7];

  int NH = in_sizes[0] / DD;
  int NT = in_sizes[1] / DD;
  int E  = in_sizes[2] / 2;
  int NL = (NH < NT) ? NH : NT;
  int E2 = E + NL;
  const int* srcA = edge;       // row 0 (h index)
  const int* dstA = edge + E;   // row 1 (t index)

  int KA = (NT + BW - 1) >> BSH;   // pass A buckets (over t / dst)
  int KB = (NH + BW - 1) >> BSH;   // pass B buckets (over h / src)
  int B  = (E2 + CHUNK - 1) / CHUNK;

  char* w = (char*)d_ws;
  size_t used = 0;
  auto alloc = [&](size_t bytes) {
    char* p = w + used; used = (used + bytes + 255) & ~(size_t)255; return p;
  };
  __hip_bfloat16* xsA = (__hip_bfloat16*)alloc((size_t)NH * HC * 2);
  __hip_bfloat16* xsB = (__hip_bfloat16*)alloc((size_t)NT * HC * 2);
  float* lsA  = (float*)alloc((size_t)NH * 2 * 4);
  float* ldB  = (float*)alloc((size_t)NH * 2 * 4);
  float* lsB  = (float*)alloc((size_t)NT * 2 * 4);
  float* ldA  = (float*)alloc((size_t)NT * 2 * 4);
  int* gcur   = (int*)alloc((size_t)(KA + KB) * 4);      // bucket cursors
  int* gcurA  = gcur;
  int* gcurB  = gcur + KA;
  int* rowT   = (int*)alloc((size_t)(NT + 1) * 4);
  int* rowH   = (int*)alloc((size_t)(NH + 1) * 4);
  unsigned int* partA = (unsigned int*)alloc((size_t)KA * CAPB * 4);  // padded
  unsigned int* partB = (unsigned int*)alloc((size_t)KB * CAPB * 4);  // padded
  int* csrT   = (int*)alloc((size_t)E2 * 4);
  int* csrH   = (int*)alloc((size_t)E2 * 4);
  unsigned short* Bt = (unsigned short*)alloc((size_t)80 * DD * 2);

  float* out   = (float*)d_out;              // (h_rep [NH,64], t_rep [NT,64])
  float* out_h = out;
  float* out_t = out + (size_t)NH * HC;

  build_bt<<<80, 128, 0, stream>>>(W_src, W_dst, att_s, att_d, Bt,
                                   gcur, KA + KB);

  int bH = (NH + 127) / 128, bT = (NT + 127) / 128;
  int nodeB = bH + bT;
  // partition blocks first [0,B), node blocks after [B, B+nodeB)
  fused_front<<<B + nodeB, 512, 0, stream>>>(
      h_x, t_x, Bt, xsA, xsB, lsA, ldB, lsB, ldA, NH, NT, bH, B,
      srcA, dstA, E, NL, gcurA, gcurB, partA, partB, KA, KB);

  bucket_csr4<<<KA + KB, 256, 0, stream>>>(
      partA, gcurA, KA, NT, partB, gcurB, KB, NH,
      E2, csrT, rowT, csrH, rowH);

  int gA = (NT + 7) / 8, gB = (NH + 7) / 8;
  csr_message5<<<gA + gB, 256, 0, stream>>>(
      rowT, csrT, lsA, ldA, xsA, out_t, NT,
      rowH, csrH, lsB, ldB, xsB, out_h, NH, bias, gA);
}